// Round 5
// baseline (287.251 us; speedup 1.0000x reference)
//
#include <hip/hip_runtime.h>
#include <stdint.h>
#include <stddef.h>

// GA3 conv2d == one dense 3x3 conv with sign-permuted weights:
//   out[b, c*8+m, h, w] = bias_eff[c*8+m]
//     + sum_{cin,k,kh,kw} s(m,k) * W[j(m,k),c,cin,kh,kw] * x[b, cin*8+k, h+kh-1, w+kw-1]
// bf16 MFMA implicit GEMM over 9 taps (K=128, split as 2 ic-halves of 64).
// R5: FULLY FUSED — no xt intermediate. Each block stages its (6 x 34) halo
// for one 64-ic half straight from NCHW f32 x into swizzled LDS bf16
// (border via predication), runs the 9-tap K-loop, restages the other half.
// LDS 25.5 KB -> 4+ blocks/CU, all 1024 blocks co-resident (no tail).

typedef __attribute__((ext_vector_type(8))) short short8;   // 8 x bf16 (4 VGPRs)
typedef __attribute__((ext_vector_type(4))) float f32x4;    // MFMA accumulator

// j(m,k) and s(m,k): unique j with S[m,j,k]!=0, transcribed from _TERMS.
__device__ __constant__ int c_J[64] = {
  0,1,2,3,4,5,6,7,
  1,0,4,6,2,7,3,5,
  2,4,0,5,1,3,7,6,
  3,6,5,0,7,2,1,4,
  4,2,1,7,0,6,5,3,
  5,7,3,2,6,0,4,1,
  6,3,7,1,5,4,0,2,
  7,5,6,4,3,1,2,0
};
__device__ __constant__ float c_Sg[64] = {
  1,1,1,1,-1,-1,-1,-1,
  1,1,-1,-1,1,-1,1,-1,
  1,1,1,-1,-1,1,1,1,
  1,1,1,1,-1,-1,-1,-1,
  1,1,-1,1,1,1,-1,1,
  1,1,1,-1,-1,1,1,1,
  1,1,-1,-1,1,-1,1,-1,
  1,1,-1,1,1,1,-1,1
};

__device__ inline unsigned short f2bf(float f) {  // RNE float->bf16
  unsigned int u = __float_as_uint(f);
  u += 0x7FFFu + ((u >> 16) & 1u);
  return (unsigned short)(u >> 16);
}
__device__ inline unsigned int packbf(float f0, float f1) {
  return (unsigned int)f2bf(f0) | ((unsigned int)f2bf(f1) << 16);
}

// ---------------- Prep B: vt in B-fragment order [t][half][kc][nt][lane][8j] + bias_eff[128] --------
// B-frag for MFMA 16x16x32: lane = quad*16+l15 holds B[k=quad*8+j][n=l15].
__global__ __launch_bounds__(256) void wprep_kernel(const float* __restrict__ W,
                                                    const float* __restrict__ bias,
                                                    unsigned short* __restrict__ vt,
                                                    float* __restrict__ beff) {
  int gid = blockIdx.x * 256 + threadIdx.x;   // 9*128*128 = 147456 threads exactly
  int t   = gid >> 14;
  int rem = gid & 16383;
  int oc  = rem >> 7;
  int ic  = rem & 127;
  int m = oc & 7, cout = oc >> 3;
  int k = ic & 7, cin = ic >> 3;
  int j = c_J[m * 8 + k];
  float s = c_Sg[m * 8 + k];
  float val = s * W[((j * 16 + cout) * 16 + cin) * 9 + t];
  int half = ic >> 6, kc = (ic >> 5) & 1, quad = (ic >> 3) & 3, jj = ic & 7;
  int nt = oc >> 4, l15 = oc & 15;
  int lane = quad * 16 + l15;
  vt[(size_t)((((t * 2 + half) * 2 + kc) * 8 + nt) * 64 + lane) * 8 + jj] = f2bf(val);
  if (gid < 128) {
    int m2 = gid & 7, cout2 = gid >> 3;
    float acc = 0.f;
    #pragma unroll
    for (int kk = 0; kk < 8; ++kk)
      acc += c_Sg[m2 * 8 + kk] * bias[c_J[m2 * 8 + kk] * 16 + cout2];
    beff[gid] = acc;
  }
}

// ---------------- Fused main: stage(half) -> 9-tap MFMA K-loop -> stage(half) -> K-loop -> store ----
// Block: 256 thr = 4 waves. Tile: 4 rows x 32 cols of pixels x 128 oc.
// Wave (wm,wn): h rows {wm*2, wm*2+1} x both w-halves x 4 n-tiles (64 oc). 64 f32 acc.
// LDS: halo (6 x 34 px) x 64 ic bf16, pixel stride 64 shorts (8 x 16B units).
// Swizzle: unit u (0..7) of pixel p stored at u' = (u ^ p) & 7.
__global__ __launch_bounds__(256, 4) void conv_kernel(const float* __restrict__ x,
                                                      const unsigned short* __restrict__ vt,
                                                      const float* __restrict__ beff,
                                                      float* __restrict__ out) {
  __shared__ __align__(16) unsigned short lds_x[6 * 34 * 64]; // 25.5 KiB
  const int tid  = threadIdx.x;
  const int bx   = blockIdx.x;    // 0..3   w tile (32)
  const int by   = blockIdx.y;    // 0..31  h tile (4)
  const int b    = blockIdx.z;    // 0..7
  const int lane = tid & 63;
  const int wave = tid >> 6;
  const int wm   = wave >> 1;     // 0..1  row pair
  const int wn   = wave & 1;      // 0..1  oc half
  const int l15  = lane & 15;
  const int quad = lane >> 4;
  const int h0 = by * 4, w0 = bx * 32;

  f32x4 acc[4][4];
  #pragma unroll
  for (int mi = 0; mi < 4; ++mi)
    #pragma unroll
    for (int ni = 0; ni < 4; ++ni)
      acc[mi][ni] = f32x4{0.f, 0.f, 0.f, 0.f};

  #pragma unroll
  for (int half = 0; half < 2; ++half) {
    __syncthreads();                    // previous K-loop's LDS reads complete
    // ---- stage interior cols (c = 1..32 -> gw = w0..w0+31): 6 rows x 32 ic-pairs x 16 col-pairs
    #pragma unroll
    for (int it = 0; it < 12; ++it) {
      int g   = it * 256 + tid;         // 0..3071
      int c16 = g & 15;                 // col pair
      int seg = g >> 4;                 // 0..191
      int r   = seg >> 5;               // 0..5
      int pi  = seg & 31;               // ic pair within half
      int ic  = half * 64 + pi * 2;
      int gh  = h0 - 1 + r;
      const float* src = x + (((size_t)(b * 128 + ic) * 128 + gh) * 128 + w0 + c16 * 2);
      float2 a0, a1;
      if ((unsigned)gh < 128u) { a0 = *(const float2*)src; a1 = *(const float2*)(src + 16384); }
      else                     { a0 = float2{0.f, 0.f};    a1 = float2{0.f, 0.f}; }
      int u = pi >> 2, lo2 = pi & 3;
      int p0 = r * 34 + c16 * 2 + 1;
      ((unsigned int*)lds_x)[p0 * 32 + ((u ^ p0) & 7) * 4 + lo2] = packbf(a0.x, a1.x);
      int p1 = p0 + 1;
      ((unsigned int*)lds_x)[p1 * 32 + ((u ^ p1) & 7) * 4 + lo2] = packbf(a0.y, a1.y);
    }
    // ---- stage edge cols (c=0 -> gw=w0-1, c=33 -> gw=w0+32): 6 rows x 32 ic-pairs x 2 sides
    #pragma unroll
    for (int it = 0; it < 2; ++it) {
      int g = it * 256 + tid;
      if (g < 384) {
        int side = g & 1, seg = g >> 1;
        int r  = seg >> 5, pi = seg & 31;
        int ic = half * 64 + pi * 2;
        int gh = h0 - 1 + r;
        int gw = side ? (w0 + 32) : (w0 - 1);
        float f0 = 0.f, f1 = 0.f;
        if ((unsigned)gh < 128u && (unsigned)gw < 128u) {
          const float* src = x + (((size_t)(b * 128 + ic) * 128 + gh) * 128 + gw);
          f0 = src[0]; f1 = src[16384];
        }
        int u = pi >> 2, lo2 = pi & 3;
        int p = r * 34 + (side ? 33 : 0);
        ((unsigned int*)lds_x)[p * 32 + ((u ^ p) & 7) * 4 + lo2] = packbf(f0, f1);
      }
    }
    __syncthreads();

    // ---- 9-tap K-loop for this ic-half (zero barriers inside)
    #pragma unroll
    for (int t = 0; t < 9; ++t) {
      const int dh = t / 3, dw = t % 3;
      int prow[4], key[4];
      #pragma unroll
      for (int mi = 0; mi < 4; ++mi) {  // mi = r*2 + w16
        int p = (wm * 2 + (mi >> 1) + dh) * 34 + ((mi & 1) * 16 + l15 + dw);
        prow[mi] = p * 64;
        key[mi]  = p & 7;
      }
      short8 bb[8];                     // B-frags from global (L2-resident, 1 KB/wave-load)
      #pragma unroll
      for (int kc = 0; kc < 2; ++kc)
        #pragma unroll
        for (int ni = 0; ni < 4; ++ni)
          bb[kc * 4 + ni] = *(const short8*)(vt +
              (size_t)((((t * 2 + half) * 2 + kc) * 8 + (wn * 4 + ni)) * 64 + lane) * 8);
      #pragma unroll
      for (int kc = 0; kc < 2; ++kc) {
        short8 a[4];
        #pragma unroll
        for (int mi = 0; mi < 4; ++mi) {
          int u2 = ((kc * 4 + quad) ^ key[mi]) & 7;
          a[mi] = *(const short8*)(lds_x + prow[mi] + u2 * 8);
        }
        #pragma unroll
        for (int mi = 0; mi < 4; ++mi)
          #pragma unroll
          for (int ni = 0; ni < 4; ++ni)
            acc[mi][ni] = __builtin_amdgcn_mfma_f32_16x16x32_bf16(a[mi], bb[kc * 4 + ni], acc[mi][ni], 0, 0, 0);
      }
    }
  }

  // ---- Epilogue: direct stores; wave covers full 128-B lines (both w16 halves of each (oc,h)).
  #pragma unroll
  for (int ni = 0; ni < 4; ++ni) {
    int oc = (wn * 4 + ni) * 16 + l15;
    float bv = beff[oc];
    #pragma unroll
    for (int r = 0; r < 2; ++r) {
      int h = h0 + wm * 2 + r;
      float* line = out + ((size_t)(b * 128 + oc) * 128 + h) * 128 + w0;
      #pragma unroll
      for (int w16 = 0; w16 < 2; ++w16) {
        f32x4 v = acc[r * 2 + w16][ni];
        v[0] += bv; v[1] += bv; v[2] += bv; v[3] += bv;
        *(f32x4*)(line + w16 * 16 + quad * 4) = v;
      }
    }
  }
}

extern "C" void kernel_launch(void* const* d_in, const int* in_sizes, int n_in,
                              void* d_out, int out_size, void* d_ws, size_t ws_size,
                              hipStream_t stream) {
  (void)in_sizes; (void)n_in; (void)out_size; (void)ws_size;
  const float* x    = (const float*)d_in[0];   // [8][128][128][128]
  const float* W    = (const float*)d_in[1];   // [8][16][16][3][3]
  const float* bias = (const float*)d_in[2];   // [8][16]
  float* out = (float*)d_out;                  // [8][128][128][128]

  const size_t VT_BYTES = (size_t)9 * 2 * 2 * 8 * 64 * 8 * 2; // 294,912
  unsigned short* vt = (unsigned short*)d_ws;
  float* beff = (float*)((char*)d_ws + VT_BYTES);

  wprep_kernel<<<dim3(576), 256, 0, stream>>>(W, bias, vt, beff);
  conv_kernel<<<dim3(4, 32, 8), 256, 0, stream>>>(x, vt, beff, out);
}